// Round 1
// baseline (491.501 us; speedup 1.0000x reference)
//
#include <hip/hip_runtime.h>
#include <stdint.h>

#define NROWS 8192   // B*S_LEN = 4*2048
#define INF   4096
#define OUTF  4096
#define RNK   1024

typedef unsigned short u16;
typedef __attribute__((ext_vector_type(8))) short bf16x8;   // 8 bf16 = 4 VGPRs
typedef __attribute__((ext_vector_type(4))) float f32x4;
typedef __attribute__((ext_vector_type(8))) unsigned short u16x8;

__device__ __forceinline__ u16 f32_bf16(float f) {
  union { float f; uint32_t u; } v; v.f = f;
  return (u16)((v.u + 0x7FFF + ((v.u >> 16) & 1)) >> 16);
}

// ---------------- conversion / dequant kernels (memory-bound) ----------------

__global__ __launch_bounds__(256) void convert_x(const float* __restrict__ x,
                                                 u16* __restrict__ o) {
  int t = blockIdx.x * 256 + threadIdx.x;
  int e = t * 8;
  float4 a = *(const float4*)(x + e);
  float4 b = *(const float4*)(x + e + 4);
  u16x8 r;
  r[0] = f32_bf16(a.x); r[1] = f32_bf16(a.y); r[2] = f32_bf16(a.z); r[3] = f32_bf16(a.w);
  r[4] = f32_bf16(b.x); r[5] = f32_bf16(b.y); r[6] = f32_bf16(b.z); r[7] = f32_bf16(b.w);
  *(u16x8*)(o + e) = r;
}

// Vh [RANK][INF]; fold dequantized S into rows of Vh.
__global__ __launch_bounds__(256) void dequant_vh(const int* __restrict__ vh,
                                                  const float* __restrict__ vs,
                                                  const float* __restrict__ vz,
                                                  const int* __restrict__ sd,
                                                  const float* __restrict__ ss,
                                                  const float* __restrict__ sz,
                                                  u16* __restrict__ o) {
  int t = blockIdx.x * 256 + threadIdx.x;
  int e = t * 4;
  int row = e >> 12;              // / INF
  float sval = ((float)sd[row] - sz[0]) * ss[0];
  float sc = vs[0] * sval;
  float zp = vz[0];
  int4 d = *(const int4*)(vh + e);
  ushort4 r;
  r.x = f32_bf16(((float)d.x - zp) * sc);
  r.y = f32_bf16(((float)d.y - zp) * sc);
  r.z = f32_bf16(((float)d.z - zp) * sc);
  r.w = f32_bf16(((float)d.w - zp) * sc);
  *(ushort4*)(o + e) = r;
}

// U [OUTF][RNK]
__global__ __launch_bounds__(256) void dequant_u(const int* __restrict__ ud,
                                                 const float* __restrict__ us,
                                                 const float* __restrict__ uz,
                                                 u16* __restrict__ o) {
  int t = blockIdx.x * 256 + threadIdx.x;
  int e = t * 4;
  float sc = us[0];
  float zp = uz[0];
  int4 d = *(const int4*)(ud + e);
  ushort4 r;
  r.x = f32_bf16(((float)d.x - zp) * sc);
  r.y = f32_bf16(((float)d.y - zp) * sc);
  r.z = f32_bf16(((float)d.z - zp) * sc);
  r.w = f32_bf16(((float)d.w - zp) * sc);
  *(ushort4*)(o + e) = r;
}

// ---------------- 8-phase counted-vmcnt bf16 GEMM (T2+T3+T4+T5) --------------
// C[m][n] = sum_k A[m][k]*B[n][k].  BM=256, BK=64, 512 threads = 8 waves (2Mx4N).
//
// Per K-tile: 4 phases. Phase (qm,qn) computes one C-quadrant and reads ONLY
// A-half qm / B-half qn of the current LDS buffer (wave wm owns interleaved
// row-blocks qm*2+wm, wave wn owns col-blocks qn*4+wn -> half index == quadrant
// index for every wave).  Stage schedule per tile t (buf=t&1, nbuf=buf^1):
//   p1 (0,0): stage B-half1 of tile t+1 -> nbuf      (region idle)
//   p2 (0,1): stage A-half1 of tile t+1 -> nbuf      (region idle)
//   p3 (1,0): stage A-half0 of tile t+2 -> buf       (A0 last read at p2)
//   p4 (1,1): stage B-half0 of tile t+2 -> buf       (B0 last read at p3)
//             then s_waitcnt vmcnt(2+LB)  == keep p3+p4 loads in flight,
//             retire everything tile t+1 needs (staged >= 5 phases earlier).
// Never vmcnt(0) in the loop (T4).  Raw s_barrier + sched_barrier(0) pinning;
// ds_read->MFMA lgkmcnt left to the compiler (it emits fine-grained waits).
// LDS XOR swizzle: 16B chunk c of row r stored at c^(r&7); global source is
// pre-permuted so global_load_lds dest stays linear (both-sides rule #21).

__device__ __forceinline__ void gl_lds16(const u16* g, u16* l) {
  __builtin_amdgcn_global_load_lds(
      (const __attribute__((address_space(1))) void*)g,
      (__attribute__((address_space(3))) void*)l, 16, 0, 0);
}

template <int VM> __device__ __forceinline__ void vm_wait() {
  static_assert(VM == 3 || VM == 4, "unexpected vmcnt");
  if constexpr (VM == 3) asm volatile("s_waitcnt vmcnt(3)" ::: "memory");
  if constexpr (VM == 4) asm volatile("s_waitcnt vmcnt(4)" ::: "memory");
}

template <int BN, int K, int N, bool OUT_BF16, bool ADD_BIAS>
__global__ __launch_bounds__(512, 2) void gemm8p(const u16* __restrict__ A,
                                                 const u16* __restrict__ B,
                                                 void* __restrict__ Cv,
                                                 const float* __restrict__ bias) {
  constexpr int BM = 256, BK = 64;
  constexpr int WN = BN / 4;            // per-wave output cols (64 or 32)
  constexpr int QJ = WN / 32;           // 16-col frags per quadrant (2 or 1)
  constexpr int LB = (BN == 256) ? 2 : 1;  // loads/thread per B half-unit
  constexpr int NT = K / BK;
  constexpr int AH = 128 * BK;          // elems per A half (16 KiB)
  constexpr int BH = (BN / 2) * BK;     // elems per B half (16 or 8 KiB)

  __shared__ __attribute__((aligned(16))) u16 ldsA[2 * 2 * AH];
  __shared__ __attribute__((aligned(16))) u16 ldsB[2 * 2 * BH];

  const int tid  = threadIdx.x;
  const int lane = tid & 63;
  const int wave = tid >> 6;            // 0..7
  const int wm   = wave >> 2;           // 0..1
  const int wn   = wave & 3;            // 0..3
  const int bm   = blockIdx.y * BM;
  const int bn   = blockIdx.x * BN;

  // staging map: thread tid writes LDS bytes [tid*16] of a unit (linear, wave-
  // contiguous as global_load_lds requires); fetches swizzled global chunk.
  const int srow = tid >> 3;            // 0..63 (round 0)
  const int spc  = tid & 7;             // physical 16B chunk
  const int sgc  = spc ^ (srow & 7);    // swizzled global chunk (row+64: same &7)

  const u16* gA = A + (size_t)(bm + srow) * K + sgc * 8;
  const u16* gB = B + (size_t)(bn + srow) * K + sgc * 8;
  u16* lA = ldsA + srow * BK + spc * 8;
  u16* lB = ldsB + srow * BK + spc * 8;

#define STAGE_A(buf, h, kt)                                                    \
  { const u16* g_ = gA + (size_t)(h) * 128 * K + (kt);                         \
    u16* l_ = lA + ((buf) * 2 + (h)) * AH;                                     \
    gl_lds16(g_, l_);                                                          \
    gl_lds16(g_ + (size_t)64 * K, l_ + 64 * BK); }

#define STAGE_B(buf, h, kt)                                                    \
  { const u16* g_ = gB + (size_t)(h) * (BN / 2) * K + (kt);                    \
    u16* l_ = lB + ((buf) * 2 + (h)) * BH;                                     \
    gl_lds16(g_, l_);                                                          \
    if constexpr (LB == 2) gl_lds16(g_ + (size_t)64 * K, l_ + 64 * BK); }

  const int r   = lane & 15;
  const int kq  = (lane >> 4) * 8;
  const int pc0 = (((kq) >> 3) ^ (r & 7)) << 3;        // phys col, k-step 0
  const int pc1 = (((32 + kq) >> 3) ^ (r & 7)) << 3;   // phys col, k-step 1

  f32x4 acc[2][2][4][QJ] = {};

#define PHASE(buf, qm, qn, STAGE, VMW)                                         \
  {                                                                            \
    bf16x8 af[4][2], bfr[QJ][2];                                               \
    const u16* abase = ldsA + ((buf) * 2 + (qm)) * AH + (wm * 64 + r) * BK;    \
    _Pragma("unroll")                                                          \
    for (int i = 0; i < 4; ++i) {                                              \
      af[i][0] = *(const bf16x8*)(abase + i * 16 * BK + pc0);                  \
      af[i][1] = *(const bf16x8*)(abase + i * 16 * BK + pc1);                  \
    }                                                                          \
    const u16* bbase =                                                         \
        ldsB + ((buf) * 2 + (qn)) * BH + (wn * (WN / 2) + r) * BK;             \
    _Pragma("unroll")                                                          \
    for (int j = 0; j < QJ; ++j) {                                             \
      bfr[j][0] = *(const bf16x8*)(bbase + j * 16 * BK + pc0);                 \
      bfr[j][1] = *(const bf16x8*)(bbase + j * 16 * BK + pc1);                 \
    }                                                                          \
    STAGE;                                                                     \
    __builtin_amdgcn_sched_barrier(0);                                         \
    __builtin_amdgcn_s_barrier();                                              \
    __builtin_amdgcn_sched_barrier(0);                                         \
    __builtin_amdgcn_s_setprio(1);                                             \
    _Pragma("unroll")                                                          \
    for (int i = 0; i < 4; ++i)                                                \
      _Pragma("unroll")                                                        \
      for (int j = 0; j < QJ; ++j) {                                           \
        acc[qm][qn][i][j] = __builtin_amdgcn_mfma_f32_16x16x32_bf16(           \
            af[i][0], bfr[j][0], acc[qm][qn][i][j], 0, 0, 0);                  \
        acc[qm][qn][i][j] = __builtin_amdgcn_mfma_f32_16x16x32_bf16(           \
            af[i][1], bfr[j][1], acc[qm][qn][i][j], 0, 0, 0);                  \
      }                                                                        \
    __builtin_amdgcn_s_setprio(0);                                             \
    __builtin_amdgcn_sched_barrier(0);                                         \
    VMW;                                                                       \
    __builtin_amdgcn_s_barrier();                                              \
    __builtin_amdgcn_sched_barrier(0);                                         \
  }

  // prologue: tile0 fully, then tile1's A0,B0 (the steady-state "(t-1).p3/p4"
  // units).  vmcnt(2+LB) retires exactly tile0, keeps tile1's 2 units flying.
  STAGE_A(0, 0, 0);
  STAGE_B(0, 0, 0);
  STAGE_B(0, 1, 0);
  STAGE_A(0, 1, 0);
  __builtin_amdgcn_sched_barrier(0);
  constexpr int KT1 = (NT > 1 ? BK : 0);
  STAGE_A(1, 0, KT1);
  STAGE_B(1, 0, KT1);
  __builtin_amdgcn_sched_barrier(0);
  vm_wait<2 + LB>();
  __builtin_amdgcn_s_barrier();
  __builtin_amdgcn_sched_barrier(0);

  for (int t = 0; t < NT; ++t) {
    const int buf  = t & 1;
    const int nbuf = buf ^ 1;
    const int kt1 = (t + 1 < NT ? t + 1 : NT - 1) * BK;  // clamp keeps vmcnt
    const int kt2 = (t + 2 < NT ? t + 2 : NT - 1) * BK;  // counts uniform
    PHASE(buf, 0, 0, STAGE_B(nbuf, 1, kt1), );
    PHASE(buf, 0, 1, STAGE_A(nbuf, 1, kt1), );
    PHASE(buf, 1, 0, STAGE_A(buf, 0, kt2), );
    PHASE(buf, 1, 1, STAGE_B(buf, 0, kt2), (vm_wait<2 + LB>()));
  }

  // epilogue: C/D layout col = lane&15, row = (lane>>4)*4 + reg  [m89-verified]
  const int col0 = lane & 15;
  const int row0 = (lane >> 4) * 4;
#pragma unroll
  for (int qm = 0; qm < 2; ++qm)
#pragma unroll
    for (int qn = 0; qn < 2; ++qn)
#pragma unroll
      for (int j = 0; j < QJ; ++j) {
        const int gcol = bn + (qn * 4 + wn) * (WN / 2) + j * 16 + col0;
        float bv = 0.f;
        if constexpr (ADD_BIAS) bv = bias[gcol];
#pragma unroll
        for (int i = 0; i < 4; ++i)
#pragma unroll
          for (int rr = 0; rr < 4; ++rr) {
            const int grow = bm + qm * 128 + wm * 64 + i * 16 + row0 + rr;
            float v = acc[qm][qn][i][j][rr] + bv;
            if constexpr (OUT_BF16)
              ((u16*)Cv)[(size_t)grow * N + gcol] = f32_bf16(v);
            else
              ((float*)Cv)[(size_t)grow * N + gcol] = v;
          }
      }
#undef PHASE
#undef STAGE_A
#undef STAGE_B
}

// ---------------- launch ----------------

extern "C" void kernel_launch(void* const* d_in, const int* in_sizes, int n_in,
                              void* d_out, int out_size, void* d_ws, size_t ws_size,
                              hipStream_t stream) {
  const float* x        = (const float*)d_in[0];
  const int*   U_data   = (const int*)d_in[1];
  const float* U_scale  = (const float*)d_in[2];
  const float* U_zp     = (const float*)d_in[3];
  const int*   S_data   = (const int*)d_in[4];
  const float* S_scale  = (const float*)d_in[5];
  const float* S_zp     = (const float*)d_in[6];
  const int*   Vh_data  = (const int*)d_in[7];
  const float* Vh_scale = (const float*)d_in[8];
  const float* Vh_zp    = (const float*)d_in[9];
  const float* bias     = (const float*)d_in[10];
  float* out = (float*)d_out;

  char* ws = (char*)d_ws;
  u16* xb  = (u16*)ws;                                  // 8192*4096*2  = 64 MiB
  u16* vhb = (u16*)(ws + (size_t)67108864);             // 1024*4096*2  =  8 MiB
  u16* ub  = (u16*)(ws + (size_t)67108864 + 8388608);   // 4096*1024*2  =  8 MiB
  u16* hb  = (u16*)(ws + (size_t)67108864 + 16777216);  // 8192*1024*2  = 16 MiB

  convert_x<<<NROWS * INF / (8 * 256), 256, 0, stream>>>(x, xb);
  dequant_vh<<<RNK * INF / (4 * 256), 256, 0, stream>>>(Vh_data, Vh_scale, Vh_zp,
                                                        S_data, S_scale, S_zp, vhb);
  dequant_u<<<OUTF * RNK / (4 * 256), 256, 0, stream>>>(U_data, U_scale, U_zp, ub);

  // GEMM1: h[8192,1024] = xb[8192,4096] @ vhb[1024,4096]^T   (bf16 out)
  // BN=128 -> grid 8x32 = 256 blocks (exactly 1/CU); BN=256 would leave half
  // the CUs idle at N=1024.
  gemm8p<128, INF, RNK, true, false>
      <<<dim3(RNK / 128, NROWS / 256), 512, 0, stream>>>(xb, vhb, (void*)hb, nullptr);

  // GEMM2: y[8192,4096] = hb[8192,1024] @ ub[4096,1024]^T + bias   (fp32 out)
  gemm8p<256, RNK, OUTF, false, true>
      <<<dim3(OUTF / 256, NROWS / 256), 512, 0, stream>>>(hb, ub, (void*)out, bias);
}

// Round 2
// 447.779 us; speedup vs baseline: 1.0976x; 1.0976x over previous
//
#include <hip/hip_runtime.h>
#include <stdint.h>

#define NROWS 8192   // B*S_LEN = 4*2048
#define INF   4096
#define OUTF  4096
#define RNK   1024

typedef unsigned short u16;
typedef __attribute__((ext_vector_type(8))) short bf16x8;   // 8 bf16 = 4 VGPRs
typedef __attribute__((ext_vector_type(4))) float f32x4;
typedef __attribute__((ext_vector_type(8))) unsigned short u16x8;

__device__ __forceinline__ u16 f32_bf16(float f) {
  union { float f; uint32_t u; } v; v.f = f;
  return (u16)((v.u + 0x7FFF + ((v.u >> 16) & 1)) >> 16);
}

// ---------------- conversion / dequant kernels (memory-bound) ----------------

__global__ __launch_bounds__(256) void convert_x(const float* __restrict__ x,
                                                 u16* __restrict__ o) {
  int t = blockIdx.x * 256 + threadIdx.x;
  int e = t * 8;
  float4 a = *(const float4*)(x + e);
  float4 b = *(const float4*)(x + e + 4);
  u16x8 r;
  r[0] = f32_bf16(a.x); r[1] = f32_bf16(a.y); r[2] = f32_bf16(a.z); r[3] = f32_bf16(a.w);
  r[4] = f32_bf16(b.x); r[5] = f32_bf16(b.y); r[6] = f32_bf16(b.z); r[7] = f32_bf16(b.w);
  *(u16x8*)(o + e) = r;
}

// Vh [RANK][INF]; fold dequantized S into rows of Vh.
__global__ __launch_bounds__(256) void dequant_vh(const int* __restrict__ vh,
                                                  const float* __restrict__ vs,
                                                  const float* __restrict__ vz,
                                                  const int* __restrict__ sd,
                                                  const float* __restrict__ ss,
                                                  const float* __restrict__ sz,
                                                  u16* __restrict__ o) {
  int t = blockIdx.x * 256 + threadIdx.x;
  int e = t * 4;
  int row = e >> 12;              // / INF
  float sval = ((float)sd[row] - sz[0]) * ss[0];
  float sc = vs[0] * sval;
  float zp = vz[0];
  int4 d = *(const int4*)(vh + e);
  ushort4 r;
  r.x = f32_bf16(((float)d.x - zp) * sc);
  r.y = f32_bf16(((float)d.y - zp) * sc);
  r.z = f32_bf16(((float)d.z - zp) * sc);
  r.w = f32_bf16(((float)d.w - zp) * sc);
  *(ushort4*)(o + e) = r;
}

// U [OUTF][RNK]
__global__ __launch_bounds__(256) void dequant_u(const int* __restrict__ ud,
                                                 const float* __restrict__ us,
                                                 const float* __restrict__ uz,
                                                 u16* __restrict__ o) {
  int t = blockIdx.x * 256 + threadIdx.x;
  int e = t * 4;
  float sc = us[0];
  float zp = uz[0];
  int4 d = *(const int4*)(ud + e);
  ushort4 r;
  r.x = f32_bf16(((float)d.x - zp) * sc);
  r.y = f32_bf16(((float)d.y - zp) * sc);
  r.z = f32_bf16(((float)d.z - zp) * sc);
  r.w = f32_bf16(((float)d.w - zp) * sc);
  *(ushort4*)(o + e) = r;
}

// -------- 4-phase counted-vmcnt bf16 GEMM with operand register reuse --------
// C[m][n] = sum_k A[m][k]*B[n][k].  BM=256, BK=64, 512 threads = 8 waves.
//
// Quadrant ring (ih,jh): (0,0) -> (0,1) -> (1,1) -> (1,0).  Fragment registers
// persist across phases so each phase issues ONLY the new operand's ds_reads:
//   p1: load af<-A0, bf0<-B0   MFMA acc[0][0]      (AI*2 + BJ*2 reads)
//   p2: load bf1<-B1           MFMA acc[0][1]      (BJ*2 reads, af reused)
//   p3: load af<-A1            MFMA acc[1][1]      (AI*2 reads, bf1 reused)
//   p4: (no reads)             MFMA acc[1][0]      (af, bf0 reused)
// Reads per K-tile per wave: GEMM2 24 (was 48), GEMM1 16 (was 40) -> the LDS
// issue pipe stops dominating the MFMA pipe (round-1 post-mortem).
//
// Staging ring (last LDS-read of A0 is p1, of B1 is p2 -> those regions are the
// "stage into buf for tile t+2" slots):
//   p1 stages A1(nbuf, t+1), p2 stages B0(nbuf, t+1),
//   p3 stages A0(buf,  t+2), p4 stages B1(buf,  t+2); then vmcnt(2+LB) keeps
//   exactly p3+p4's loads in flight (never 0 in the loop), barrier.
// LDS XOR swizzle: 16B chunk c of row r stored at c^(r&7); global source is
// pre-permuted so global_load_lds dest stays linear (both-sides rule).

__device__ __forceinline__ void gl_lds16(const u16* g, u16* l) {
  __builtin_amdgcn_global_load_lds(
      (const __attribute__((address_space(1))) void*)g,
      (__attribute__((address_space(3))) void*)l, 16, 0, 0);
}

template <int VM> __device__ __forceinline__ void vm_wait() {
  static_assert(VM == 3 || VM == 4, "unexpected vmcnt");
  if constexpr (VM == 3) asm volatile("s_waitcnt vmcnt(3)" ::: "memory");
  if constexpr (VM == 4) asm volatile("s_waitcnt vmcnt(4)" ::: "memory");
}

template <int BN, int WM, int WN, int K, int N, bool OUT_BF16, bool ADD_BIAS>
__global__ __launch_bounds__(512, 2) void gemm4p(const u16* __restrict__ A,
                                                 const u16* __restrict__ B,
                                                 void* __restrict__ Cv,
                                                 const float* __restrict__ bias) {
  constexpr int BM = 256, BK = 64;
  constexpr int AR = 128 / WM;          // per-wave rows inside an A-half
  constexpr int BC = (BN / 2) / WN;     // per-wave cols inside a B-half
  constexpr int AI = AR / 16;           // A frags per phase
  constexpr int BJ = BC / 16;           // B frags per phase
  constexpr int LB = (BN == 256) ? 2 : 1;  // gl_lds rounds per B half
  constexpr int NT = K / BK;
  constexpr int AH = 128 * BK;          // elems per A half (16 KiB)
  constexpr int BH = (BN / 2) * BK;     // elems per B half (16 or 8 KiB)

  __shared__ __attribute__((aligned(16))) u16 ldsA[2 * 2 * AH];
  __shared__ __attribute__((aligned(16))) u16 ldsB[2 * 2 * BH];

  const int tid  = threadIdx.x;
  const int lane = tid & 63;
  const int wave = tid >> 6;            // 0..7
  const int wn   = wave % WN;
  const int wm   = wave / WN;
  const int bm   = blockIdx.y * BM;
  const int bn   = blockIdx.x * BN;

  // staging map: thread tid writes LDS bytes [tid*16] of a unit (linear, as
  // global_load_lds requires); fetches the swizzled global 16B chunk.
  const int srow = tid >> 3;            // 0..63
  const int spc  = tid & 7;             // physical 16B chunk
  const int sgc  = spc ^ (srow & 7);    // swizzled global chunk

  const u16* gA = A + (size_t)(bm + srow) * K + sgc * 8;
  const u16* gB = B + (size_t)(bn + srow) * K + sgc * 8;
  u16* lA = ldsA + srow * BK + spc * 8;
  u16* lB = ldsB + srow * BK + spc * 8;

#define STAGE_A(buf, h, kt)                                                    \
  { const u16* g_ = gA + (size_t)(h) * 128 * K + (kt);                         \
    u16* l_ = lA + ((buf) * 2 + (h)) * AH;                                     \
    gl_lds16(g_, l_);                                                          \
    gl_lds16(g_ + (size_t)64 * K, l_ + 64 * BK); }

#define STAGE_B(buf, h, kt)                                                    \
  { const u16* g_ = gB + (size_t)(h) * (BN / 2) * K + (kt);                    \
    u16* l_ = lB + ((buf) * 2 + (h)) * BH;                                     \
    gl_lds16(g_, l_);                                                          \
    if constexpr (LB == 2) gl_lds16(g_ + (size_t)64 * K, l_ + 64 * BK); }

  const int r   = lane & 15;
  const int kq  = (lane >> 4) * 8;
  const int pc0 = (((kq) >> 3) ^ (r & 7)) << 3;        // phys col, k-step 0
  const int pc1 = (((32 + kq) >> 3) ^ (r & 7)) << 3;   // phys col, k-step 1

  f32x4 acc[2][2][AI][BJ] = {};
  bf16x8 af[AI][2];    // current A-half frags (p1->p2 hold A0, p3->p4 hold A1)
  bf16x8 bf0[BJ][2];   // B-half0 frags, live the whole K-tile (p1 and p4)
  bf16x8 bf1[BJ][2];   // B-half1 frags (p2->p3)

#define LOAD_A(buf, ih)                                                        \
  { const u16* ab = ldsA + ((buf) * 2 + (ih)) * AH + (wm * AR + r) * BK;       \
    _Pragma("unroll")                                                          \
    for (int i = 0; i < AI; ++i) {                                             \
      af[i][0] = *(const bf16x8*)(ab + i * 16 * BK + pc0);                     \
      af[i][1] = *(const bf16x8*)(ab + i * 16 * BK + pc1);                     \
    } }

#define LOAD_B(dst, buf, jh)                                                   \
  { const u16* bb = ldsB + ((buf) * 2 + (jh)) * BH + (wn * BC + r) * BK;       \
    _Pragma("unroll")                                                          \
    for (int j = 0; j < BJ; ++j) {                                             \
      dst[j][0] = *(const bf16x8*)(bb + j * 16 * BK + pc0);                    \
      dst[j][1] = *(const bf16x8*)(bb + j * 16 * BK + pc1);                    \
    } }

#define MFMA_Q(ih, jh, bsrc)                                                   \
  _Pragma("unroll")                                                            \
  for (int i = 0; i < AI; ++i)                                                 \
    _Pragma("unroll")                                                          \
    for (int j = 0; j < BJ; ++j) {                                             \
      acc[ih][jh][i][j] = __builtin_amdgcn_mfma_f32_16x16x32_bf16(             \
          af[i][0], bsrc[j][0], acc[ih][jh][i][j], 0, 0, 0);                   \
      acc[ih][jh][i][j] = __builtin_amdgcn_mfma_f32_16x16x32_bf16(             \
          af[i][1], bsrc[j][1], acc[ih][jh][i][j], 0, 0, 0);                   \
    }

#define SB  __builtin_amdgcn_sched_barrier(0)
#define BAR __builtin_amdgcn_s_barrier()
#define PRIO1 __builtin_amdgcn_s_setprio(1)
#define PRIO0 __builtin_amdgcn_s_setprio(0)

  // prologue: tile0 fully; then tile1's steady-state in-flight pair {A0, B1}.
  STAGE_A(0, 0, 0);
  STAGE_B(0, 0, 0);
  STAGE_B(0, 1, 0);
  STAGE_A(0, 1, 0);
  SB;
  constexpr int KT1 = (NT > 1 ? BK : 0);
  STAGE_A(1, 0, KT1);
  STAGE_B(1, 1, KT1);
  SB;
  vm_wait<2 + LB>();
  BAR;
  SB;

  for (int t = 0; t < NT; ++t) {
    const int buf  = t & 1;
    const int nbuf = buf ^ 1;
    const int kt1 = (t + 1 < NT ? t + 1 : NT - 1) * BK;  // clamp keeps vmcnt
    const int kt2 = (t + 2 < NT ? t + 2 : NT - 1) * BK;  // counts uniform

    // p1 (0,0): fresh A0 + B0
    LOAD_A(buf, 0); LOAD_B(bf0, buf, 0);
    STAGE_A(nbuf, 1, kt1);
    SB; BAR; SB; PRIO1;
    MFMA_Q(0, 0, bf0);
    PRIO0; SB; BAR; SB;

    // p2 (0,1): fresh B1, reuse af(A0)
    LOAD_B(bf1, buf, 1);
    STAGE_B(nbuf, 0, kt1);
    SB; BAR; SB; PRIO1;
    MFMA_Q(0, 1, bf1);
    PRIO0; SB; BAR; SB;

    // p3 (1,1): fresh A1, reuse bf1(B1)
    LOAD_A(buf, 1);
    STAGE_A(buf, 0, kt2);
    SB; BAR; SB; PRIO1;
    MFMA_Q(1, 1, bf1);
    PRIO0; SB; BAR; SB;

    // p4 (1,0): no LDS reads, reuse af(A1) x bf0(B0)
    STAGE_B(buf, 1, kt2);
    SB; BAR; SB; PRIO1;
    MFMA_Q(1, 0, bf0);
    PRIO0; SB;
    vm_wait<2 + LB>();
    BAR; SB;
  }

  // epilogue: C/D layout col = lane&15, row = (lane>>4)*4 + reg  [m89-verified]
  const int col0 = lane & 15;
  const int row0 = (lane >> 4) * 4;
#pragma unroll
  for (int ih = 0; ih < 2; ++ih)
#pragma unroll
    for (int jh = 0; jh < 2; ++jh)
#pragma unroll
      for (int j = 0; j < BJ; ++j) {
        const int gcol = bn + jh * (BN / 2) + wn * BC + j * 16 + col0;
        float bv = 0.f;
        if constexpr (ADD_BIAS) bv = bias[gcol];
#pragma unroll
        for (int i = 0; i < AI; ++i)
#pragma unroll
          for (int rr = 0; rr < 4; ++rr) {
            const int grow = bm + ih * 128 + wm * AR + i * 16 + row0 + rr;
            float v = acc[ih][jh][i][j][rr] + bv;
            if constexpr (OUT_BF16)
              ((u16*)Cv)[(size_t)grow * N + gcol] = f32_bf16(v);
            else
              ((float*)Cv)[(size_t)grow * N + gcol] = v;
          }
      }
#undef MFMA_Q
#undef LOAD_A
#undef LOAD_B
#undef STAGE_A
#undef STAGE_B
#undef SB
#undef BAR
#undef PRIO1
#undef PRIO0
}

// ---------------- launch ----------------

extern "C" void kernel_launch(void* const* d_in, const int* in_sizes, int n_in,
                              void* d_out, int out_size, void* d_ws, size_t ws_size,
                              hipStream_t stream) {
  const float* x        = (const float*)d_in[0];
  const int*   U_data   = (const int*)d_in[1];
  const float* U_scale  = (const float*)d_in[2];
  const float* U_zp     = (const float*)d_in[3];
  const int*   S_data   = (const int*)d_in[4];
  const float* S_scale  = (const float*)d_in[5];
  const float* S_zp     = (const float*)d_in[6];
  const int*   Vh_data  = (const int*)d_in[7];
  const float* Vh_scale = (const float*)d_in[8];
  const float* Vh_zp    = (const float*)d_in[9];
  const float* bias     = (const float*)d_in[10];
  float* out = (float*)d_out;

  char* ws = (char*)d_ws;
  u16* xb  = (u16*)ws;                                  // 8192*4096*2  = 64 MiB
  u16* vhb = (u16*)(ws + (size_t)67108864);             // 1024*4096*2  =  8 MiB
  u16* ub  = (u16*)(ws + (size_t)67108864 + 8388608);   // 4096*1024*2  =  8 MiB
  u16* hb  = (u16*)(ws + (size_t)67108864 + 16777216);  // 8192*1024*2  = 16 MiB

  convert_x<<<NROWS * INF / (8 * 256), 256, 0, stream>>>(x, xb);
  dequant_vh<<<RNK * INF / (4 * 256), 256, 0, stream>>>(Vh_data, Vh_scale, Vh_zp,
                                                        S_data, S_scale, S_zp, vhb);
  dequant_u<<<OUTF * RNK / (4 * 256), 256, 0, stream>>>(U_data, U_scale, U_zp, ub);

  // GEMM1: h[8192,1024] = xb[8192,4096] @ vhb[1024,4096]^T   (bf16 out)
  // waves 4Mx2N -> per-wave 64x64: balances A/B LDS traffic at BN=128.
  gemm4p<128, 4, 2, INF, RNK, true, false>
      <<<dim3(RNK / 128, NROWS / 256), 512, 0, stream>>>(xb, vhb, (void*)hb, nullptr);

  // GEMM2: y[8192,4096] = hb[8192,1024] @ ub[4096,1024]^T + bias   (fp32 out)
  // waves 2Mx4N -> per-wave 128x64 (m201 geometry).
  gemm4p<256, 2, 4, RNK, OUTF, false, true>
      <<<dim3(OUTF / 256, NROWS / 256), 512, 0, stream>>>(hb, ub, (void*)out, bias);
}

// Round 3
// 418.014 us; speedup vs baseline: 1.1758x; 1.0712x over previous
//
#include <hip/hip_runtime.h>
#include <stdint.h>

#define NROWS 8192   // B*S_LEN = 4*2048
#define INF   4096
#define OUTF  4096
#define RNK   1024

typedef unsigned short u16;
typedef __attribute__((ext_vector_type(8))) short bf16x8;   // 8 bf16 = 4 VGPRs
typedef __attribute__((ext_vector_type(4))) float f32x4;
typedef __attribute__((ext_vector_type(8))) unsigned short u16x8;

__device__ __forceinline__ u16 f32_bf16(float f) {
  union { float f; uint32_t u; } v; v.f = f;
  return (u16)((v.u + 0x7FFF + ((v.u >> 16) & 1)) >> 16);
}

// ---------------- conversion / dequant kernels (memory-bound) ----------------

__global__ __launch_bounds__(256) void convert_x(const float* __restrict__ x,
                                                 u16* __restrict__ o) {
  int t = blockIdx.x * 256 + threadIdx.x;
  int e = t * 8;
  float4 a = *(const float4*)(x + e);
  float4 b = *(const float4*)(x + e + 4);
  u16x8 r;
  r[0] = f32_bf16(a.x); r[1] = f32_bf16(a.y); r[2] = f32_bf16(a.z); r[3] = f32_bf16(a.w);
  r[4] = f32_bf16(b.x); r[5] = f32_bf16(b.y); r[6] = f32_bf16(b.z); r[7] = f32_bf16(b.w);
  *(u16x8*)(o + e) = r;
}

// Vh [RANK][INF]; fold dequantized S into rows of Vh.
__global__ __launch_bounds__(256) void dequant_vh(const int* __restrict__ vh,
                                                  const float* __restrict__ vs,
                                                  const float* __restrict__ vz,
                                                  const int* __restrict__ sd,
                                                  const float* __restrict__ ss,
                                                  const float* __restrict__ sz,
                                                  u16* __restrict__ o) {
  int t = blockIdx.x * 256 + threadIdx.x;
  int e = t * 4;
  int row = e >> 12;              // / INF
  float sval = ((float)sd[row] - sz[0]) * ss[0];
  float sc = vs[0] * sval;
  float zp = vz[0];
  int4 d = *(const int4*)(vh + e);
  ushort4 r;
  r.x = f32_bf16(((float)d.x - zp) * sc);
  r.y = f32_bf16(((float)d.y - zp) * sc);
  r.z = f32_bf16(((float)d.z - zp) * sc);
  r.w = f32_bf16(((float)d.w - zp) * sc);
  *(ushort4*)(o + e) = r;
}

// U [OUTF][RNK]
__global__ __launch_bounds__(256) void dequant_u(const int* __restrict__ ud,
                                                 const float* __restrict__ us,
                                                 const float* __restrict__ uz,
                                                 u16* __restrict__ o) {
  int t = blockIdx.x * 256 + threadIdx.x;
  int e = t * 4;
  float sc = us[0];
  float zp = uz[0];
  int4 d = *(const int4*)(ud + e);
  ushort4 r;
  r.x = f32_bf16(((float)d.x - zp) * sc);
  r.y = f32_bf16(((float)d.y - zp) * sc);
  r.z = f32_bf16(((float)d.z - zp) * sc);
  r.w = f32_bf16(((float)d.w - zp) * sc);
  *(ushort4*)(o + e) = r;
}

// -------- 4-phase counted-vmcnt bf16 GEMM with operand register reuse --------
// C[m][n] = sum_k A[m][k]*B[n][k].  BM=256, BK=64, 512 threads = 8 waves.
//
// Quadrant ring (ih,jh): (0,0) -> (0,1) -> (1,1) -> (1,0); fragment registers
// persist so each phase issues only the NEW operand's ds_reads (round-2 fix).
//
// Round-3 additions (GEMM1 was staging-volume-bound at 6.8 TB/s effective vs
// the 10.5 TB/s the round-0 kernel demonstrated):
//  * T1 XCD-chunked blockIdx swizzle (both GEMMs): each XCD owns a contiguous
//    sub-grid -> operand panels are fetched once per XCD and L2-served after.
//  * NBUF=3 for GEMM1 (LDS 144 KiB): stage the ENTIRE tile t+2 during tile t
//    into buffer (t+2)%3 (free all tile -> no region juggling), vmcnt(6) at
//    tile end = 6 loads in flight with 4-8 phases of flight time (2x depth).
//    GEMM2 keeps the 2-buffer ring (3rd buffer would need 192 KiB > 160).

__device__ __forceinline__ void gl_lds16(const u16* g, u16* l) {
  __builtin_amdgcn_global_load_lds(
      (const __attribute__((address_space(1))) void*)g,
      (__attribute__((address_space(3))) void*)l, 16, 0, 0);
}

template <int VM> __device__ __forceinline__ void vm_wait() {
  static_assert(VM == 3 || VM == 4 || VM == 6, "unexpected vmcnt");
  if constexpr (VM == 3) asm volatile("s_waitcnt vmcnt(3)" ::: "memory");
  if constexpr (VM == 4) asm volatile("s_waitcnt vmcnt(4)" ::: "memory");
  if constexpr (VM == 6) asm volatile("s_waitcnt vmcnt(6)" ::: "memory");
}

template <int BN, int WM, int WN, int K, int N, int NBUF, bool OUT_BF16, bool ADD_BIAS>
__global__ __launch_bounds__(512, 2) void gemm4p(const u16* __restrict__ A,
                                                 const u16* __restrict__ B,
                                                 void* __restrict__ Cv,
                                                 const float* __restrict__ bias) {
  constexpr int BM = 256, BK = 64;
  constexpr int AR = 128 / WM;          // per-wave rows inside an A-half
  constexpr int BC = (BN / 2) / WN;     // per-wave cols inside a B-half
  constexpr int AI = AR / 16;           // A frags per phase
  constexpr int BJ = BC / 16;           // B frags per phase
  constexpr int LB = (BN == 256) ? 2 : 1;  // gl_lds rounds per B half
  constexpr int NT = K / BK;
  constexpr int AH = 128 * BK;          // elems per A half (16 KiB)
  constexpr int BH = (BN / 2) * BK;     // elems per B half (16 or 8 KiB)

  constexpr int NXB = N / BN;           // grid x (N-blocks)
  constexpr int NYB = NROWS / BM;       // grid y (M-blocks)
  constexpr int NWG = NXB * NYB;
  static_assert(NWG % 8 == 0, "XCD swizzle requires nwg % 8 == 0");
  constexpr int CPX = NWG / 8;          // blocks per XCD chunk

  __shared__ __attribute__((aligned(16))) u16 ldsA[NBUF * 2 * AH];
  __shared__ __attribute__((aligned(16))) u16 ldsB[NBUF * 2 * BH];

  const int tid  = threadIdx.x;
  const int lane = tid & 63;
  const int wave = tid >> 6;            // 0..7
  const int wn   = wave % WN;
  const int wm   = wave / WN;

  // T1: XCD-chunked swizzle.  HW round-robins linear id % 8 across XCDs; remap
  // so XCD k owns contiguous original ids [k*CPX, (k+1)*CPX) = a (NYB/8)-row x
  // NXB-col chunk -> A/B panels L2-resident per XCD.
  const int L    = blockIdx.y * NXB + blockIdx.x;
  const int orig = (L & 7) * CPX + (L >> 3);
  const int bm   = (orig / NXB) * BM;
  const int bn   = (orig % NXB) * BN;

  // staging map: thread tid writes LDS bytes [tid*16] of a unit (linear, as
  // global_load_lds requires); fetches the swizzled global 16B chunk.
  const int srow = tid >> 3;            // 0..63
  const int spc  = tid & 7;             // physical 16B chunk
  const int sgc  = spc ^ (srow & 7);    // swizzled global chunk

  const u16* gA = A + (size_t)(bm + srow) * K + sgc * 8;
  const u16* gB = B + (size_t)(bn + srow) * K + sgc * 8;
  u16* lA = ldsA + srow * BK + spc * 8;
  u16* lB = ldsB + srow * BK + spc * 8;

#define STAGE_A(buf, h, kt)                                                    \
  { const u16* g_ = gA + (size_t)(h) * 128 * K + (kt);                         \
    u16* l_ = lA + ((buf) * 2 + (h)) * AH;                                     \
    gl_lds16(g_, l_);                                                          \
    gl_lds16(g_ + (size_t)64 * K, l_ + 64 * BK); }

#define STAGE_B(buf, h, kt)                                                    \
  { const u16* g_ = gB + (size_t)(h) * (BN / 2) * K + (kt);                    \
    u16* l_ = lB + ((buf) * 2 + (h)) * BH;                                     \
    gl_lds16(g_, l_);                                                          \
    if constexpr (LB == 2) gl_lds16(g_ + (size_t)64 * K, l_ + 64 * BK); }

  const int r   = lane & 15;
  const int kq  = (lane >> 4) * 8;
  const int pc0 = (((kq) >> 3) ^ (r & 7)) << 3;        // phys col, k-step 0
  const int pc1 = (((32 + kq) >> 3) ^ (r & 7)) << 3;   // phys col, k-step 1

  f32x4 acc[2][2][AI][BJ] = {};
  bf16x8 af[AI][2];    // current A-half frags (p1->p2 hold A0, p3->p4 hold A1)
  bf16x8 bf0[BJ][2];   // B-half0 frags, live the whole K-tile (p1 and p4)
  bf16x8 bf1[BJ][2];   // B-half1 frags (p2->p3)

#define LOAD_A(buf, ih)                                                        \
  { const u16* ab = ldsA + ((buf) * 2 + (ih)) * AH + (wm * AR + r) * BK;       \
    _Pragma("unroll")                                                          \
    for (int i = 0; i < AI; ++i) {                                             \
      af[i][0] = *(const bf16x8*)(ab + i * 16 * BK + pc0);                     \
      af[i][1] = *(const bf16x8*)(ab + i * 16 * BK + pc1);                     \
    } }

#define LOAD_B(dst, buf, jh)                                                   \
  { const u16* bb = ldsB + ((buf) * 2 + (jh)) * BH + (wn * BC + r) * BK;       \
    _Pragma("unroll")                                                          \
    for (int j = 0; j < BJ; ++j) {                                             \
      dst[j][0] = *(const bf16x8*)(bb + j * 16 * BK + pc0);                    \
      dst[j][1] = *(const bf16x8*)(bb + j * 16 * BK + pc1);                    \
    } }

#define MFMA_Q(ih, jh, bsrc)                                                   \
  _Pragma("unroll")                                                            \
  for (int i = 0; i < AI; ++i)                                                 \
    _Pragma("unroll")                                                          \
    for (int j = 0; j < BJ; ++j) {                                             \
      acc[ih][jh][i][j] = __builtin_amdgcn_mfma_f32_16x16x32_bf16(             \
          af[i][0], bsrc[j][0], acc[ih][jh][i][j], 0, 0, 0);                   \
      acc[ih][jh][i][j] = __builtin_amdgcn_mfma_f32_16x16x32_bf16(             \
          af[i][1], bsrc[j][1], acc[ih][jh][i][j], 0, 0, 0);                   \
    }

#define SB  __builtin_amdgcn_sched_barrier(0)
#define BAR __builtin_amdgcn_s_barrier()
#define PRIO1 __builtin_amdgcn_s_setprio(1)
#define PRIO0 __builtin_amdgcn_s_setprio(0)

  if constexpr (NBUF == 3) {
    // -------- deep pipeline: whole tile t+2 staged during tile t --------
    // per-tile loads = 6 (A halves 2+2, B halves 1+1; LB==1 path only).
    static_assert(LB == 1, "NBUF==3 path sized for BN==128");
    STAGE_A(0, 0, 0); STAGE_B(0, 0, 0); STAGE_A(0, 1, 0); STAGE_B(0, 1, 0);
    constexpr int KT1 = (NT > 1 ? BK : 0);
    STAGE_A(1, 0, KT1); STAGE_B(1, 0, KT1); STAGE_A(1, 1, KT1); STAGE_B(1, 1, KT1);
    SB;
    vm_wait<6>();       // retire tile0, keep tile1's 6 loads in flight
    BAR; SB;

    int buf = 0, bufn = 1, sbuf = 2;
    for (int t = 0; t < NT; ++t) {
      const int kt2 = (t + 2 < NT ? t + 2 : NT - 1) * BK;  // clamp: uniform cnt

      // p1 (0,0): fresh A0 + B0
      LOAD_A(buf, 0); LOAD_B(bf0, buf, 0);
      STAGE_A(sbuf, 0, kt2);
      SB; BAR; SB; PRIO1;
      MFMA_Q(0, 0, bf0);
      PRIO0; SB; BAR; SB;

      // p2 (0,1): fresh B1, reuse af(A0)
      LOAD_B(bf1, buf, 1);
      STAGE_B(sbuf, 0, kt2);
      SB; BAR; SB; PRIO1;
      MFMA_Q(0, 1, bf1);
      PRIO0; SB; BAR; SB;

      // p3 (1,1): fresh A1, reuse bf1(B1)
      LOAD_A(buf, 1);
      STAGE_A(sbuf, 1, kt2);
      SB; BAR; SB; PRIO1;
      MFMA_Q(1, 1, bf1);
      PRIO0; SB; BAR; SB;

      // p4 (1,0): no LDS reads, reuse af(A1) x bf0(B0)
      STAGE_B(sbuf, 1, kt2);
      SB; BAR; SB; PRIO1;
      MFMA_Q(1, 0, bf0);
      PRIO0; SB;
      vm_wait<6>();     // retire tile t+1's loads, keep tile t+2's 6 in flight
      BAR; SB;

      const int tmp = buf; buf = bufn; bufn = sbuf; sbuf = tmp;
    }
  } else {
    // -------- 2-buffer ring (round-2 structure, unchanged) --------
    STAGE_A(0, 0, 0);
    STAGE_B(0, 0, 0);
    STAGE_B(0, 1, 0);
    STAGE_A(0, 1, 0);
    SB;
    constexpr int KT1 = (NT > 1 ? BK : 0);
    STAGE_A(1, 0, KT1);
    STAGE_B(1, 1, KT1);
    SB;
    vm_wait<2 + LB>();
    BAR; SB;

    for (int t = 0; t < NT; ++t) {
      const int buf  = t & 1;
      const int nbuf = buf ^ 1;
      const int kt1 = (t + 1 < NT ? t + 1 : NT - 1) * BK;
      const int kt2 = (t + 2 < NT ? t + 2 : NT - 1) * BK;

      // p1 (0,0): fresh A0 + B0
      LOAD_A(buf, 0); LOAD_B(bf0, buf, 0);
      STAGE_A(nbuf, 1, kt1);
      SB; BAR; SB; PRIO1;
      MFMA_Q(0, 0, bf0);
      PRIO0; SB; BAR; SB;

      // p2 (0,1): fresh B1, reuse af(A0)
      LOAD_B(bf1, buf, 1);
      STAGE_B(nbuf, 0, kt1);
      SB; BAR; SB; PRIO1;
      MFMA_Q(0, 1, bf1);
      PRIO0; SB; BAR; SB;

      // p3 (1,1): fresh A1, reuse bf1(B1)
      LOAD_A(buf, 1);
      STAGE_A(buf, 0, kt2);
      SB; BAR; SB; PRIO1;
      MFMA_Q(1, 1, bf1);
      PRIO0; SB; BAR; SB;

      // p4 (1,0): no LDS reads, reuse af(A1) x bf0(B0)
      STAGE_B(buf, 1, kt2);
      SB; BAR; SB; PRIO1;
      MFMA_Q(1, 0, bf0);
      PRIO0; SB;
      vm_wait<2 + LB>();
      BAR; SB;
    }
  }

  // epilogue: C/D layout col = lane&15, row = (lane>>4)*4 + reg  [m89-verified]
  const int col0 = lane & 15;
  const int row0 = (lane >> 4) * 4;
#pragma unroll
  for (int ih = 0; ih < 2; ++ih)
#pragma unroll
    for (int jh = 0; jh < 2; ++jh)
#pragma unroll
      for (int j = 0; j < BJ; ++j) {
        const int gcol = bn + jh * (BN / 2) + wn * BC + j * 16 + col0;
        float bv = 0.f;
        if constexpr (ADD_BIAS) bv = bias[gcol];
#pragma unroll
        for (int i = 0; i < AI; ++i)
#pragma unroll
          for (int rr = 0; rr < 4; ++rr) {
            const int grow = bm + ih * 128 + wm * AR + i * 16 + row0 + rr;
            float v = acc[ih][jh][i][j][rr] + bv;
            if constexpr (OUT_BF16)
              ((u16*)Cv)[(size_t)grow * N + gcol] = f32_bf16(v);
            else
              ((float*)Cv)[(size_t)grow * N + gcol] = v;
          }
      }
#undef MFMA_Q
#undef LOAD_A
#undef LOAD_B
#undef STAGE_A
#undef STAGE_B
#undef SB
#undef BAR
#undef PRIO1
#undef PRIO0
}

// ---------------- launch ----------------

extern "C" void kernel_launch(void* const* d_in, const int* in_sizes, int n_in,
                              void* d_out, int out_size, void* d_ws, size_t ws_size,
                              hipStream_t stream) {
  const float* x        = (const float*)d_in[0];
  const int*   U_data   = (const int*)d_in[1];
  const float* U_scale  = (const float*)d_in[2];
  const float* U_zp     = (const float*)d_in[3];
  const int*   S_data   = (const int*)d_in[4];
  const float* S_scale  = (const float*)d_in[5];
  const float* S_zp     = (const float*)d_in[6];
  const int*   Vh_data  = (const int*)d_in[7];
  const float* Vh_scale = (const float*)d_in[8];
  const float* Vh_zp    = (const float*)d_in[9];
  const float* bias     = (const float*)d_in[10];
  float* out = (float*)d_out;

  char* ws = (char*)d_ws;
  u16* xb  = (u16*)ws;                                  // 8192*4096*2  = 64 MiB
  u16* vhb = (u16*)(ws + (size_t)67108864);             // 1024*4096*2  =  8 MiB
  u16* ub  = (u16*)(ws + (size_t)67108864 + 8388608);   // 4096*1024*2  =  8 MiB
  u16* hb  = (u16*)(ws + (size_t)67108864 + 16777216);  // 8192*1024*2  = 16 MiB

  convert_x<<<NROWS * INF / (8 * 256), 256, 0, stream>>>(x, xb);
  dequant_vh<<<RNK * INF / (4 * 256), 256, 0, stream>>>(Vh_data, Vh_scale, Vh_zp,
                                                        S_data, S_scale, S_zp, vhb);
  dequant_u<<<OUTF * RNK / (4 * 256), 256, 0, stream>>>(U_data, U_scale, U_zp, ub);

  // GEMM1: h[8192,1024] = xb[8192,4096] @ vhb[1024,4096]^T   (bf16 out)
  // waves 4Mx2N (64x64/wave); NBUF=3 deep pipeline (LDS 144 KiB); XCD swizzle.
  gemm4p<128, 4, 2, INF, RNK, 3, true, false>
      <<<dim3(RNK / 128, NROWS / 256), 512, 0, stream>>>(xb, vhb, (void*)hb, nullptr);

  // GEMM2: y[8192,4096] = hb[8192,1024] @ ub[4096,1024]^T + bias   (fp32 out)
  // waves 2Mx4N (128x64/wave); 2-buffer ring; XCD swizzle.
  gemm4p<256, 2, 4, RNK, OUTF, 2, false, true>
      <<<dim3(OUTF / 256, NROWS / 256), 512, 0, stream>>>(hb, ub, (void*)out, bias);
}